// Round 1
// baseline (409.837 us; speedup 1.0000x reference)
//
#include <hip/hip_runtime.h>
#include <hip/hip_bf16.h>
#include <math.h>

// Problem constants (derived at launch from in_sizes where possible)
#define HIDDEN 256
#define NCLS 10

// ---------------------------------------------------------------------------
// Graph preprocessing kernels (run once per launch; ws is not preserved)
// ---------------------------------------------------------------------------

__global__ void k_init(int* ecnt, int* cursor, int N) {
    int i = blockIdx.x * blockDim.x + threadIdx.x;
    if (i < N) { ecnt[i] = 0; cursor[i] = 0; }
}

__global__ void k_count(const int* __restrict__ dst, int* __restrict__ ecnt, int E) {
    int e = blockIdx.x * blockDim.x + threadIdx.x;
    if (e < E) atomicAdd(&ecnt[dst[e]], 1);
}

__global__ void k_dinv(const int* __restrict__ ecnt, float* __restrict__ dinv, int N) {
    int i = blockIdx.x * blockDim.x + threadIdx.x;
    if (i < N) {
        float deg = (float)(ecnt[i] + 1);  // +1 self loop
        dinv[i] = rsqrtf(deg);
    }
}

// single-block exclusive scan of ecnt -> rowstart (N+1 entries)
__global__ void k_scan(const int* __restrict__ ecnt, int* __restrict__ rowstart, int N, int E) {
    __shared__ int sums[1024];
    int t = threadIdx.x;
    const int CH = (N + 1023) / 1024;
    int base = t * CH;
    int local = 0;
    for (int i = 0; i < CH; ++i) {
        int idx = base + i;
        if (idx < N) local += ecnt[idx];
    }
    sums[t] = local;
    __syncthreads();
    // Hillis-Steele inclusive scan
    for (int off = 1; off < 1024; off <<= 1) {
        int v = (t >= off) ? sums[t - off] : 0;
        __syncthreads();
        sums[t] += v;
        __syncthreads();
    }
    int run = (t == 0) ? 0 : sums[t - 1];
    for (int i = 0; i < CH; ++i) {
        int idx = base + i;
        if (idx < N) { rowstart[idx] = run; run += ecnt[idx]; }
    }
    if (t == 0) rowstart[N] = E;
}

__global__ void k_fill(const int* __restrict__ src, const int* __restrict__ dst,
                       const float* __restrict__ dinv,
                       const int* __restrict__ rowstart, int* __restrict__ cursor,
                       int* __restrict__ csr_src, float* __restrict__ csr_w, int E) {
    int e = blockIdx.x * blockDim.x + threadIdx.x;
    if (e < E) {
        int d = dst[e];
        int s = src[e];
        int pos = rowstart[d] + atomicAdd(&cursor[d], 1);
        csr_src[pos] = s;
        csr_w[pos]   = dinv[s] * dinv[d];
    }
}

// ---------------------------------------------------------------------------
// GEMM: C[M,256] = act(A)[M,256] @ W[256,256]   (act = optional ReLU on input)
// Block: 256 threads, 8 rows per block staged in LDS; thread t owns column t.
// ---------------------------------------------------------------------------
template <bool RELU_IN>
__global__ __launch_bounds__(256) void k_gemm(const float* __restrict__ A,
                                              const float* __restrict__ W,
                                              float* __restrict__ C, int M) {
    __shared__ float xs[8][HIDDEN];
    const int t = threadIdx.x;
    const int row0 = blockIdx.x * 8;
#pragma unroll
    for (int r = 0; r < 8; ++r) {
        float v = A[(size_t)(row0 + r) * HIDDEN + t];
        if (RELU_IN) v = fmaxf(v, 0.f);
        xs[r][t] = v;
    }
    __syncthreads();

    float acc[8];
#pragma unroll
    for (int r = 0; r < 8; ++r) acc[r] = 0.f;

    const int col = t;
    for (int k = 0; k < HIDDEN; k += 4) {
        float w0 = W[(size_t)(k + 0) * HIDDEN + col];
        float w1 = W[(size_t)(k + 1) * HIDDEN + col];
        float w2 = W[(size_t)(k + 2) * HIDDEN + col];
        float w3 = W[(size_t)(k + 3) * HIDDEN + col];
#pragma unroll
        for (int r = 0; r < 8; ++r) {
            const float4 xv = *reinterpret_cast<const float4*>(&xs[r][k]);
            acc[r] = fmaf(xv.x, w0, acc[r]);
            acc[r] = fmaf(xv.y, w1, acc[r]);
            acc[r] = fmaf(xv.z, w2, acc[r]);
            acc[r] = fmaf(xv.w, w3, acc[r]);
        }
    }
#pragma unroll
    for (int r = 0; r < 8; ++r) C[(size_t)(row0 + r) * HIDDEN + col] = acc[r];
}

// ---------------------------------------------------------------------------
// Aggregation: out[n][c] = sum_{e in CSR(n)} H[src_e][c]*w_e + H[n][c]*dinv[n]^2 + b[c]
// One block (256 threads) per node; thread c owns channel c. No atomics.
// ---------------------------------------------------------------------------
__global__ __launch_bounds__(256) void k_agg(const float* __restrict__ H,
                                             const int* __restrict__ csr_src,
                                             const float* __restrict__ csr_w,
                                             const int* __restrict__ rowstart,
                                             const float* __restrict__ dinv,
                                             const float* __restrict__ bias,
                                             float* __restrict__ out) {
    const int n = blockIdx.x;
    const int c = threadIdx.x;
    const float di = dinv[n];
    float acc = H[(size_t)n * HIDDEN + c] * di * di;
    const int s0 = rowstart[n], s1 = rowstart[n + 1];
    for (int e = s0; e < s1; ++e) {
        int s = csr_src[e];
        float w = csr_w[e];
        acc = fmaf(H[(size_t)s * HIDDEN + c], w, acc);
    }
    out[(size_t)n * HIDDEN + c] = acc + bias[c];
}

// ---------------------------------------------------------------------------
// Mean pooling over sorted batch assignment: one block per graph.
// Applies ReLU to input (last conv's output).
// ---------------------------------------------------------------------------
__device__ __forceinline__ int lower_bound_i(const int* a, int n, int val) {
    int lo = 0, hi = n;
    while (lo < hi) {
        int mid = (lo + hi) >> 1;
        if (a[mid] < val) lo = mid + 1; else hi = mid;
    }
    return lo;
}

__global__ __launch_bounds__(256) void k_pool(const float* __restrict__ H,
                                              const int* __restrict__ batch,
                                              float* __restrict__ pooled, int N) {
    const int g = blockIdx.x;
    const int c = threadIdx.x;
    const int lo = lower_bound_i(batch, N, g);
    const int hi = lower_bound_i(batch, N, g + 1);
    float s = 0.f;
    for (int i = lo; i < hi; ++i) s += fmaxf(H[(size_t)i * HIDDEN + c], 0.f);
    float cnt = (float)(hi - lo);
    pooled[(size_t)g * HIDDEN + c] = s / fmaxf(cnt, 1.f);
}

// ---------------------------------------------------------------------------
// Classifier: logits = pooled @ Wlin + blin; log_softmax. One block per graph.
// ---------------------------------------------------------------------------
__global__ __launch_bounds__(256) void k_cls(const float* __restrict__ pooled,
                                             const float* __restrict__ Wlin,
                                             const float* __restrict__ blin,
                                             float* __restrict__ out) {
    __shared__ float part[NCLS][HIDDEN];
    const int g = blockIdx.x;
    const int t = threadIdx.x;
    const float p = pooled[(size_t)g * HIDDEN + t];
#pragma unroll
    for (int c = 0; c < NCLS; ++c) part[c][t] = p * Wlin[(size_t)t * NCLS + c];
    __syncthreads();
    for (int off = 128; off >= 1; off >>= 1) {
        if (t < off) {
#pragma unroll
            for (int c = 0; c < NCLS; ++c) part[c][t] += part[c][t + off];
        }
        __syncthreads();
    }
    if (t == 0) {
        float lg[NCLS];
        float m = -INFINITY;
#pragma unroll
        for (int c = 0; c < NCLS; ++c) {
            lg[c] = part[c][0] + blin[c];
            m = fmaxf(m, lg[c]);
        }
        float se = 0.f;
#pragma unroll
        for (int c = 0; c < NCLS; ++c) se += expf(lg[c] - m);
        float lse = m + logf(se);
#pragma unroll
        for (int c = 0; c < NCLS; ++c) out[(size_t)g * NCLS + c] = lg[c] - lse;
    }
}

// ---------------------------------------------------------------------------

extern "C" void kernel_launch(void* const* d_in, const int* in_sizes, int n_in,
                              void* d_out, int out_size, void* d_ws, size_t ws_size,
                              hipStream_t stream) {
    const float* x    = (const float*)d_in[0];
    const float* W1   = (const float*)d_in[1];
    const float* b1   = (const float*)d_in[2];
    const float* W2   = (const float*)d_in[3];
    const float* b2   = (const float*)d_in[4];
    const float* W3   = (const float*)d_in[5];
    const float* b3   = (const float*)d_in[6];
    const float* Wlin = (const float*)d_in[7];
    const float* blin = (const float*)d_in[8];
    const int*   eidx = (const int*)d_in[9];
    const int*   batch= (const int*)d_in[10];
    float* out = (float*)d_out;

    const int N = in_sizes[0] / HIDDEN;      // 10000
    const int E = in_sizes[9] / 2;           // 320000
    const int G = out_size / NCLS;           // 64

    const int* src = eidx;
    const int* dst = eidx + E;

    // workspace layout
    char* base = (char*)d_ws;
    size_t off = 0;
    auto alloc = [&](size_t bytes) -> void* {
        void* p = base + off;
        off = (off + bytes + 255) & ~(size_t)255;
        return p;
    };
    int*   ecnt     = (int*)  alloc((size_t)N * sizeof(int));
    int*   cursor   = (int*)  alloc((size_t)N * sizeof(int));
    float* dinv     = (float*)alloc((size_t)N * sizeof(float));
    int*   rowstart = (int*)  alloc((size_t)(N + 1) * sizeof(int));
    int*   csr_src  = (int*)  alloc((size_t)E * sizeof(int));
    float* csr_w    = (float*)alloc((size_t)E * sizeof(float));
    float* hA       = (float*)alloc((size_t)N * HIDDEN * sizeof(float));
    float* hB       = (float*)alloc((size_t)N * HIDDEN * sizeof(float));
    float* pooled   = (float*)alloc((size_t)G * HIDDEN * sizeof(float));
    (void)ws_size;

    const int T = 256;
    // --- graph preprocessing (per call; ws not preserved between replays) ---
    k_init <<<(N + T - 1) / T, T, 0, stream>>>(ecnt, cursor, N);
    k_count<<<(E + T - 1) / T, T, 0, stream>>>(dst, ecnt, E);
    k_dinv <<<(N + T - 1) / T, T, 0, stream>>>(ecnt, dinv, N);
    k_scan <<<1, 1024, 0, stream>>>(ecnt, rowstart, N, E);
    k_fill <<<(E + T - 1) / T, T, 0, stream>>>(src, dst, dinv, rowstart, cursor,
                                               csr_src, csr_w, E);

    const int gemm_blocks = (N + 7) / 8;   // 1250
    // --- layer 1 ---
    k_gemm<false><<<gemm_blocks, T, 0, stream>>>(x, W1, hA, N);
    k_agg<<<N, T, 0, stream>>>(hA, csr_src, csr_w, rowstart, dinv, b1, hB);
    // --- layer 2 (ReLU fused into GEMM input read) ---
    k_gemm<true><<<gemm_blocks, T, 0, stream>>>(hB, W2, hA, N);
    k_agg<<<N, T, 0, stream>>>(hA, csr_src, csr_w, rowstart, dinv, b2, hB);
    // --- layer 3 ---
    k_gemm<true><<<gemm_blocks, T, 0, stream>>>(hB, W3, hA, N);
    k_agg<<<N, T, 0, stream>>>(hA, csr_src, csr_w, rowstart, dinv, b3, hB);
    // --- pool (ReLU fused) + classifier ---
    k_pool<<<G, T, 0, stream>>>(hB, batch, pooled, N);
    k_cls <<<G, T, 0, stream>>>(pooled, Wlin, blin, out);
}

// Round 2
// 215.801 us; speedup vs baseline: 1.8991x; 1.8991x over previous
//
#include <hip/hip_runtime.h>
#include <hip/hip_bf16.h>
#include <math.h>

#define HIDDEN 256
#define NCLS 10

typedef __attribute__((ext_vector_type(8))) short short8;
typedef __attribute__((ext_vector_type(4))) float f32x4;

// ---- bf16 helpers (bit-level, RTNE) ---------------------------------------
static __device__ __forceinline__ float bf16lo(unsigned u) {
    return __uint_as_float((u & 0xffffu) << 16);
}
static __device__ __forceinline__ float bf16hi(unsigned u) {
    return __uint_as_float(u & 0xffff0000u);
}
static __device__ __forceinline__ unsigned short f2bf(float f) {
    unsigned x = __float_as_uint(f);
    x += 0x7fffu + ((x >> 16) & 1u);       // round-to-nearest-even
    return (unsigned short)(x >> 16);
}
static __device__ __forceinline__ unsigned pack2(float lo, float hi) {
    return (unsigned)f2bf(lo) | ((unsigned)f2bf(hi) << 16);
}

// ---------------------------------------------------------------------------
// Graph preprocessing (per call; ws not preserved between replays)
// ---------------------------------------------------------------------------
__global__ void k_init(int* ecnt, int* cursor, int N) {
    int i = blockIdx.x * blockDim.x + threadIdx.x;
    if (i < N) { ecnt[i] = 0; cursor[i] = 0; }
}

__global__ void k_count(const int* __restrict__ dst, int* __restrict__ ecnt, int E) {
    int e = blockIdx.x * blockDim.x + threadIdx.x;
    if (e < E) atomicAdd(&ecnt[dst[e]], 1);
}

__global__ void k_dinv(const int* __restrict__ ecnt, float* __restrict__ dinv, int N) {
    int i = blockIdx.x * blockDim.x + threadIdx.x;
    if (i < N) dinv[i] = rsqrtf((float)(ecnt[i] + 1));   // +1 self loop
}

__global__ void k_scan(const int* __restrict__ ecnt, int* __restrict__ rowstart, int N, int E) {
    __shared__ int sums[1024];
    int t = threadIdx.x;
    const int CH = (N + 1023) / 1024;
    int base = t * CH;
    int local = 0;
    for (int i = 0; i < CH; ++i) {
        int idx = base + i;
        if (idx < N) local += ecnt[idx];
    }
    sums[t] = local;
    __syncthreads();
    for (int off = 1; off < 1024; off <<= 1) {
        int v = (t >= off) ? sums[t - off] : 0;
        __syncthreads();
        sums[t] += v;
        __syncthreads();
    }
    int run = (t == 0) ? 0 : sums[t - 1];
    for (int i = 0; i < CH; ++i) {
        int idx = base + i;
        if (idx < N) { rowstart[idx] = run; run += ecnt[idx]; }
    }
    if (t == 0) rowstart[N] = E;
}

__global__ void k_fill(const int* __restrict__ src, const int* __restrict__ dst,
                       const float* __restrict__ dinv,
                       const int* __restrict__ rowstart, int* __restrict__ cursor,
                       int* __restrict__ csr_src, float* __restrict__ csr_w, int E) {
    int e = blockIdx.x * blockDim.x + threadIdx.x;
    if (e < E) {
        int d = dst[e];
        int s = src[e];
        int pos = rowstart[d] + atomicAdd(&cursor[d], 1);
        csr_src[pos] = s;
        csr_w[pos]   = dinv[s] * dinv[d];
    }
}

// ---------------------------------------------------------------------------
// Convert f32 -> bf16 (4 floats / thread)
// ---------------------------------------------------------------------------
__global__ void k_cvt(const float* __restrict__ in, unsigned* __restrict__ out, int n4) {
    int i = blockIdx.x * blockDim.x + threadIdx.x;
    if (i < n4) {
        float4 v = reinterpret_cast<const float4*>(in)[i];
        uint2 o;
        o.x = pack2(v.x, v.y);
        o.y = pack2(v.z, v.w);
        reinterpret_cast<uint2*>(out)[i] = o;
    }
}

// ---------------------------------------------------------------------------
// Pack W [256x256] f32 row-major into MFMA B-fragments (bf16).
// Fragment id = (s*16 + t)*64 + lane ; elements j=0..7 : W[32s + 8*(l>>4)+j][16t + (l&15)]
// ---------------------------------------------------------------------------
__global__ void k_packW(const float* __restrict__ W, short8* __restrict__ P) {
    int id = blockIdx.x * blockDim.x + threadIdx.x;   // 0..8191
    int l = id & 63;
    int t = (id >> 6) & 15;
    int s = id >> 10;
    int col = t * 16 + (l & 15);
    int k0 = s * 32 + (l >> 4) * 8;
    short8 v;
#pragma unroll
    for (int j = 0; j < 8; ++j)
        v[j] = (short)f2bf(W[(size_t)(k0 + j) * HIDDEN + col]);
    P[id] = v;
}

// ---------------------------------------------------------------------------
// MFMA GEMM: C[Mp,256] = A[Mp,256] @ W (pre-packed).  bf16 in, bf16 out.
// Block 256 thr = 4 waves; wave w: rows blockIdx.x*64 + 16w, cols blockIdx.y*64.
// 4 n-fragments per wave, K=256 fully unrolled (8 steps of K32).
// k-permutation-safe: A and B fragments use the same k formula, so any internal
// MFMA k-ordering cancels; only lane->row/col (std) + C/D map (m89) assumed.
// ---------------------------------------------------------------------------
__global__ __launch_bounds__(256) void k_gemm(const unsigned short* __restrict__ A,
                                              const short8* __restrict__ P,
                                              unsigned short* __restrict__ C) {
    const int l = threadIdx.x & 63;
    const int w = threadIdx.x >> 6;
    const int g = l >> 4;
    const int r = l & 15;
    const int mwave = blockIdx.x * 64 + w * 16;
    const int nb = blockIdx.y * 4;

    f32x4 acc[4] = {f32x4{0,0,0,0}, f32x4{0,0,0,0}, f32x4{0,0,0,0}, f32x4{0,0,0,0}};
    const unsigned short* arow = A + (size_t)(mwave + r) * HIDDEN;

#pragma unroll
    for (int s = 0; s < 8; ++s) {
        short8 a = *reinterpret_cast<const short8*>(arow + s * 32 + g * 8);
#pragma unroll
        for (int f = 0; f < 4; ++f) {
            short8 b = P[(s * 16 + nb + f) * 64 + l];
            acc[f] = __builtin_amdgcn_mfma_f32_16x16x32_bf16(a, b, acc[f], 0, 0, 0);
        }
    }
#pragma unroll
    for (int f = 0; f < 4; ++f) {
        int col = blockIdx.y * 64 + f * 16 + r;
#pragma unroll
        for (int q = 0; q < 4; ++q) {
            int row = mwave + g * 4 + q;
            C[(size_t)row * HIDDEN + col] = f2bf(acc[f][q]);
        }
    }
}

// ---------------------------------------------------------------------------
// Aggregation (bf16 H): out[n] = relu( sum_e H[src]*w + H[n]*dinv^2 + b )
// Block = 128 threads, one node; thread t owns channels {2t, 2t+1} (one uint).
// ---------------------------------------------------------------------------
__global__ __launch_bounds__(128) void k_agg(const unsigned* __restrict__ H,
                                             const int* __restrict__ csr_src,
                                             const float* __restrict__ csr_w,
                                             const int* __restrict__ rowstart,
                                             const float* __restrict__ dinv,
                                             const float* __restrict__ bias,
                                             unsigned* __restrict__ out) {
    const int n = blockIdx.x;
    const int t = threadIdx.x;
    const float di = dinv[n];
    const unsigned su = H[n * 128 + t];
    float ax = bf16lo(su) * di * di;
    float ay = bf16hi(su) * di * di;

    int e = rowstart[n];
    const int e1 = rowstart[n + 1];
    for (; e + 4 <= e1; e += 4) {
        int s0 = csr_src[e], s1 = csr_src[e + 1], s2 = csr_src[e + 2], s3 = csr_src[e + 3];
        float w0 = csr_w[e], w1 = csr_w[e + 1], w2 = csr_w[e + 2], w3 = csr_w[e + 3];
        unsigned u0 = H[s0 * 128 + t];
        unsigned u1 = H[s1 * 128 + t];
        unsigned u2 = H[s2 * 128 + t];
        unsigned u3 = H[s3 * 128 + t];
        ax = fmaf(bf16lo(u0), w0, ax); ay = fmaf(bf16hi(u0), w0, ay);
        ax = fmaf(bf16lo(u1), w1, ax); ay = fmaf(bf16hi(u1), w1, ay);
        ax = fmaf(bf16lo(u2), w2, ax); ay = fmaf(bf16hi(u2), w2, ay);
        ax = fmaf(bf16lo(u3), w3, ax); ay = fmaf(bf16hi(u3), w3, ay);
    }
    for (; e < e1; ++e) {
        int s = csr_src[e];
        float wv = csr_w[e];
        unsigned u = H[s * 128 + t];
        ax = fmaf(bf16lo(u), wv, ax);
        ay = fmaf(bf16hi(u), wv, ay);
    }
    float ox = fmaxf(ax + bias[2 * t], 0.f);
    float oy = fmaxf(ay + bias[2 * t + 1], 0.f);
    out[n * 128 + t] = pack2(ox, oy);
}

// ---------------------------------------------------------------------------
// Mean pool (ReLU already applied in agg). Grid (G, 2), block 64.
// ---------------------------------------------------------------------------
__device__ __forceinline__ int lower_bound_i(const int* a, int n, int val) {
    int lo = 0, hi = n;
    while (lo < hi) {
        int mid = (lo + hi) >> 1;
        if (a[mid] < val) lo = mid + 1; else hi = mid;
    }
    return lo;
}

__global__ __launch_bounds__(64) void k_pool(const unsigned* __restrict__ H,
                                             const int* __restrict__ batch,
                                             float* __restrict__ pooled, int N) {
    const int g = blockIdx.x;
    const int p = blockIdx.y * 64 + threadIdx.x;   // channel pair 0..127
    const int lo = lower_bound_i(batch, N, g);
    const int hi = lower_bound_i(batch, N, g + 1);
    float sx = 0.f, sy = 0.f;
    for (int i = lo; i < hi; ++i) {
        unsigned u = H[i * 128 + p];
        sx += bf16lo(u);
        sy += bf16hi(u);
    }
    float inv = 1.f / fmaxf((float)(hi - lo), 1.f);
    pooled[g * HIDDEN + 2 * p]     = sx * inv;
    pooled[g * HIDDEN + 2 * p + 1] = sy * inv;
}

// ---------------------------------------------------------------------------
// Classifier: logits = pooled @ Wlin + blin; log_softmax. One block per graph.
// ---------------------------------------------------------------------------
__global__ __launch_bounds__(256) void k_cls(const float* __restrict__ pooled,
                                             const float* __restrict__ Wlin,
                                             const float* __restrict__ blin,
                                             float* __restrict__ out) {
    __shared__ float part[NCLS][HIDDEN];
    const int g = blockIdx.x;
    const int t = threadIdx.x;
    const float p = pooled[(size_t)g * HIDDEN + t];
#pragma unroll
    for (int c = 0; c < NCLS; ++c) part[c][t] = p * Wlin[(size_t)t * NCLS + c];
    __syncthreads();
    for (int off = 128; off >= 1; off >>= 1) {
        if (t < off) {
#pragma unroll
            for (int c = 0; c < NCLS; ++c) part[c][t] += part[c][t + off];
        }
        __syncthreads();
    }
    if (t == 0) {
        float lg[NCLS];
        float m = -INFINITY;
#pragma unroll
        for (int c = 0; c < NCLS; ++c) {
            lg[c] = part[c][0] + blin[c];
            m = fmaxf(m, lg[c]);
        }
        float se = 0.f;
#pragma unroll
        for (int c = 0; c < NCLS; ++c) se += expf(lg[c] - m);
        float lse = m + logf(se);
#pragma unroll
        for (int c = 0; c < NCLS; ++c) out[(size_t)g * NCLS + c] = lg[c] - lse;
    }
}

// ---------------------------------------------------------------------------

extern "C" void kernel_launch(void* const* d_in, const int* in_sizes, int n_in,
                              void* d_out, int out_size, void* d_ws, size_t ws_size,
                              hipStream_t stream) {
    const float* x    = (const float*)d_in[0];
    const float* W1   = (const float*)d_in[1];
    const float* b1   = (const float*)d_in[2];
    const float* W2   = (const float*)d_in[3];
    const float* b2   = (const float*)d_in[4];
    const float* W3   = (const float*)d_in[5];
    const float* b3   = (const float*)d_in[6];
    const float* Wlin = (const float*)d_in[7];
    const float* blin = (const float*)d_in[8];
    const int*   eidx = (const int*)d_in[9];
    const int*   batch= (const int*)d_in[10];
    float* out = (float*)d_out;

    const int N = in_sizes[0] / HIDDEN;      // 10000
    const int E = in_sizes[9] / 2;           // 320000
    const int G = out_size / NCLS;           // 64
    const int Mp = (N + 63) & ~63;           // 10048 (pad rows read poison, never consumed)

    const int* src = eidx;
    const int* dst = eidx + E;

    char* base = (char*)d_ws;
    size_t off = 0;
    auto alloc = [&](size_t bytes) -> void* {
        void* p = base + off;
        off = (off + bytes + 255) & ~(size_t)255;
        return p;
    };
    int*      ecnt     = (int*)     alloc((size_t)N * sizeof(int));
    int*      cursor   = (int*)     alloc((size_t)N * sizeof(int));
    float*    dinv     = (float*)   alloc((size_t)N * sizeof(float));
    int*      rowstart = (int*)     alloc((size_t)(N + 1) * sizeof(int));
    int*      csr_src  = (int*)     alloc((size_t)E * sizeof(int));
    float*    csr_w    = (float*)   alloc((size_t)E * sizeof(float));
    unsigned* x16      = (unsigned*)alloc((size_t)Mp * 128 * sizeof(unsigned));
    unsigned* hA       = (unsigned*)alloc((size_t)Mp * 128 * sizeof(unsigned));
    unsigned* hB       = (unsigned*)alloc((size_t)Mp * 128 * sizeof(unsigned));
    short8*   Wp1      = (short8*)  alloc((size_t)8192 * sizeof(short8));
    short8*   Wp2      = (short8*)  alloc((size_t)8192 * sizeof(short8));
    short8*   Wp3      = (short8*)  alloc((size_t)8192 * sizeof(short8));
    float*    pooled   = (float*)   alloc((size_t)G * HIDDEN * sizeof(float));
    (void)ws_size;

    const int T = 256;
    // --- graph preprocessing ---
    k_init <<<(N + T - 1) / T, T, 0, stream>>>(ecnt, cursor, N);
    k_count<<<(E + T - 1) / T, T, 0, stream>>>(dst, ecnt, E);
    k_dinv <<<(N + T - 1) / T, T, 0, stream>>>(ecnt, dinv, N);
    k_scan <<<1, 1024, 0, stream>>>(ecnt, rowstart, N, E);
    k_fill <<<(E + T - 1) / T, T, 0, stream>>>(src, dst, dinv, rowstart, cursor,
                                               csr_src, csr_w, E);
    // --- dtype prep ---
    const int n4 = N * HIDDEN / 4;
    k_cvt  <<<(n4 + T - 1) / T, T, 0, stream>>>(x, x16, n4);
    k_packW<<<8192 / T, T, 0, stream>>>(W1, Wp1);
    k_packW<<<8192 / T, T, 0, stream>>>(W2, Wp2);
    k_packW<<<8192 / T, T, 0, stream>>>(W3, Wp3);

    const dim3 ggrid(Mp / 64, 4);
    // --- layer 1 ---
    k_gemm<<<ggrid, T, 0, stream>>>((const unsigned short*)x16, Wp1, (unsigned short*)hA);
    k_agg <<<N, 128, 0, stream>>>(hA, csr_src, csr_w, rowstart, dinv, b1, hB);
    // --- layer 2 ---
    k_gemm<<<ggrid, T, 0, stream>>>((const unsigned short*)hB, Wp2, (unsigned short*)hA);
    k_agg <<<N, 128, 0, stream>>>(hA, csr_src, csr_w, rowstart, dinv, b2, hB);
    // --- layer 3 ---
    k_gemm<<<ggrid, T, 0, stream>>>((const unsigned short*)hB, Wp3, (unsigned short*)hA);
    k_agg <<<N, 128, 0, stream>>>(hA, csr_src, csr_w, rowstart, dinv, b3, hB);
    // --- pool + classifier ---
    k_pool<<<dim3(G, 2), 64, 0, stream>>>(hB, batch, pooled, N);
    k_cls <<<G, T, 0, stream>>>(pooled, Wlin, blin, out);
}

// Round 3
// 181.611 us; speedup vs baseline: 2.2567x; 1.1883x over previous
//
#include <hip/hip_runtime.h>
#include <hip/hip_bf16.h>
#include <math.h>

#define HIDDEN 256
#define NCLS 10

typedef __attribute__((ext_vector_type(8))) short short8;
typedef __attribute__((ext_vector_type(4))) float f32x4;

// ---- bf16 helpers (bit-level, RTNE) ---------------------------------------
static __device__ __forceinline__ float bf16lo(unsigned u) {
    return __uint_as_float((u & 0xffffu) << 16);
}
static __device__ __forceinline__ float bf16hi(unsigned u) {
    return __uint_as_float(u & 0xffff0000u);
}
static __device__ __forceinline__ unsigned short f2bf(float f) {
    unsigned x = __float_as_uint(f);
    x += 0x7fffu + ((x >> 16) & 1u);       // round-to-nearest-even
    return (unsigned short)(x >> 16);
}
static __device__ __forceinline__ unsigned pack2(float lo, float hi) {
    return (unsigned)f2bf(lo) | ((unsigned)f2bf(hi) << 16);
}

static __device__ __forceinline__ void fma8(float* acc, uint4 u, float w) {
    acc[0] = fmaf(bf16lo(u.x), w, acc[0]);
    acc[1] = fmaf(bf16hi(u.x), w, acc[1]);
    acc[2] = fmaf(bf16lo(u.y), w, acc[2]);
    acc[3] = fmaf(bf16hi(u.y), w, acc[3]);
    acc[4] = fmaf(bf16lo(u.z), w, acc[4]);
    acc[5] = fmaf(bf16hi(u.z), w, acc[5]);
    acc[6] = fmaf(bf16lo(u.w), w, acc[6]);
    acc[7] = fmaf(bf16hi(u.w), w, acc[7]);
}

// ---------------------------------------------------------------------------
// Graph preprocessing (per call; ws not preserved between replays)
// ---------------------------------------------------------------------------
__global__ void k_init(int* ecnt, int* cursor, int N) {
    int i = blockIdx.x * blockDim.x + threadIdx.x;
    if (i < N) { ecnt[i] = 0; cursor[i] = 0; }
}

__global__ void k_count(const int* __restrict__ dst, int* __restrict__ ecnt, int E) {
    int e = blockIdx.x * blockDim.x + threadIdx.x;
    if (e < E) atomicAdd(&ecnt[dst[e]], 1);
}

__global__ void k_dinv(const int* __restrict__ ecnt, float* __restrict__ dinv, int N) {
    int i = blockIdx.x * blockDim.x + threadIdx.x;
    if (i < N) dinv[i] = rsqrtf((float)(ecnt[i] + 1));   // +1 self loop
}

__global__ void k_scan(const int* __restrict__ ecnt, int* __restrict__ rowstart, int N, int E) {
    __shared__ int sums[1024];
    int t = threadIdx.x;
    const int CH = (N + 1023) / 1024;
    int base = t * CH;
    int local = 0;
    for (int i = 0; i < CH; ++i) {
        int idx = base + i;
        if (idx < N) local += ecnt[idx];
    }
    sums[t] = local;
    __syncthreads();
    for (int off = 1; off < 1024; off <<= 1) {
        int v = (t >= off) ? sums[t - off] : 0;
        __syncthreads();
        sums[t] += v;
        __syncthreads();
    }
    int run = (t == 0) ? 0 : sums[t - 1];
    for (int i = 0; i < CH; ++i) {
        int idx = base + i;
        if (idx < N) { rowstart[idx] = run; run += ecnt[idx]; }
    }
    if (t == 0) rowstart[N] = E;
}

// packed CSR entry: .x = src node, .y = bits of edge weight
__global__ void k_fill(const int* __restrict__ src, const int* __restrict__ dst,
                       const float* __restrict__ dinv,
                       const int* __restrict__ rowstart, int* __restrict__ cursor,
                       uint2* __restrict__ csr, int E) {
    int e = blockIdx.x * blockDim.x + threadIdx.x;
    if (e < E) {
        int d = dst[e];
        int s = src[e];
        int pos = rowstart[d] + atomicAdd(&cursor[d], 1);
        uint2 ent;
        ent.x = (unsigned)s;
        ent.y = __float_as_uint(dinv[s] * dinv[d]);
        csr[pos] = ent;
    }
}

// ---------------------------------------------------------------------------
// Convert f32 -> bf16 (4 floats / thread)
// ---------------------------------------------------------------------------
__global__ void k_cvt(const float* __restrict__ in, unsigned* __restrict__ out, int n4) {
    int i = blockIdx.x * blockDim.x + threadIdx.x;
    if (i < n4) {
        float4 v = reinterpret_cast<const float4*>(in)[i];
        uint2 o;
        o.x = pack2(v.x, v.y);
        o.y = pack2(v.z, v.w);
        reinterpret_cast<uint2*>(out)[i] = o;
    }
}

// ---------------------------------------------------------------------------
// Pack W [256x256] f32 row-major into MFMA B-fragments (bf16).
// Fragment id = (s*16 + t)*64 + lane ; elements j: W[32s + 8*(l>>4)+j][16t + (l&15)]
// ---------------------------------------------------------------------------
__global__ void k_packW(const float* __restrict__ W, short8* __restrict__ P) {
    int id = blockIdx.x * blockDim.x + threadIdx.x;   // 0..8191
    int l = id & 63;
    int t = (id >> 6) & 15;
    int s = id >> 10;
    int col = t * 16 + (l & 15);
    int k0 = s * 32 + (l >> 4) * 8;
    short8 v;
#pragma unroll
    for (int j = 0; j < 8; ++j)
        v[j] = (short)f2bf(W[(size_t)(k0 + j) * HIDDEN + col]);
    P[id] = v;
}

// ---------------------------------------------------------------------------
// MFMA GEMM: C[Mp,256] = A[Mp,256] @ W (pre-packed).  bf16 in, bf16 out.
// Block 256 thr = 4 waves; wave w: rows blockIdx.x*64 + 16w, cols blockIdx.y*64.
// k-permutation-safe: A and B fragments use the same k formula.
// ---------------------------------------------------------------------------
__global__ __launch_bounds__(256) void k_gemm(const unsigned short* __restrict__ A,
                                              const short8* __restrict__ P,
                                              unsigned short* __restrict__ C) {
    const int l = threadIdx.x & 63;
    const int w = threadIdx.x >> 6;
    const int g = l >> 4;
    const int r = l & 15;
    const int mwave = blockIdx.x * 64 + w * 16;
    const int nb = blockIdx.y * 4;

    f32x4 acc[4] = {f32x4{0,0,0,0}, f32x4{0,0,0,0}, f32x4{0,0,0,0}, f32x4{0,0,0,0}};
    const unsigned short* arow = A + (size_t)(mwave + r) * HIDDEN;

#pragma unroll
    for (int s = 0; s < 8; ++s) {
        short8 a = *reinterpret_cast<const short8*>(arow + s * 32 + g * 8);
#pragma unroll
        for (int f = 0; f < 4; ++f) {
            short8 b = P[(s * 16 + nb + f) * 64 + l];
            acc[f] = __builtin_amdgcn_mfma_f32_16x16x32_bf16(a, b, acc[f], 0, 0, 0);
        }
    }
#pragma unroll
    for (int f = 0; f < 4; ++f) {
        int col = blockIdx.y * 64 + f * 16 + r;
#pragma unroll
        for (int q = 0; q < 4; ++q) {
            int row = mwave + g * 4 + q;
            C[(size_t)row * HIDDEN + col] = f2bf(acc[f][q]);
        }
    }
}

// ---------------------------------------------------------------------------
// Aggregation (bf16 H): out[n] = relu( sum_e H[src]*w + H[n]*dinv^2 + b )
// One WAVE (64 lanes) per node. Lane l: channel chunk q=l&31 (8 ch via dwordx4),
// edge phase h=l>>5 (halves take alternate edges). Cross-half combine: shfl_xor.
// ---------------------------------------------------------------------------
__global__ __launch_bounds__(64) void k_agg(const unsigned* __restrict__ H,
                                            const uint2* __restrict__ csr,
                                            const int* __restrict__ rowstart,
                                            const float* __restrict__ dinv,
                                            const float* __restrict__ bias,
                                            unsigned* __restrict__ out) {
    const int n = blockIdx.x;
    const int l = threadIdx.x;
    const int q = l & 31;
    const int h = l >> 5;
    const uint4* __restrict__ H4 = reinterpret_cast<const uint4*>(H);

    float acc[8] = {0.f, 0.f, 0.f, 0.f, 0.f, 0.f, 0.f, 0.f};
    if (h == 0) {
        const float di = dinv[n];
        fma8(acc, H4[(size_t)n * 32 + q], di * di);
    }

    int e = rowstart[n] + h;
    const int e1 = rowstart[n + 1];
    for (; e + 2 < e1; e += 4) {
        uint2 ed0 = csr[e];
        uint2 ed1 = csr[e + 2];
        uint4 r0 = H4[(size_t)ed0.x * 32 + q];
        uint4 r1 = H4[(size_t)ed1.x * 32 + q];
        fma8(acc, r0, __uint_as_float(ed0.y));
        fma8(acc, r1, __uint_as_float(ed1.y));
    }
    for (; e < e1; e += 2) {
        uint2 ed = csr[e];
        uint4 r0 = H4[(size_t)ed.x * 32 + q];
        fma8(acc, r0, __uint_as_float(ed.y));
    }

#pragma unroll
    for (int j = 0; j < 8; ++j) acc[j] += __shfl_xor(acc[j], 32);

    if (h == 0) {
        const float4* __restrict__ b4 = reinterpret_cast<const float4*>(bias);
        float4 ba = b4[q * 2];
        float4 bb = b4[q * 2 + 1];
        uint4 o;
        o.x = pack2(fmaxf(acc[0] + ba.x, 0.f), fmaxf(acc[1] + ba.y, 0.f));
        o.y = pack2(fmaxf(acc[2] + ba.z, 0.f), fmaxf(acc[3] + ba.w, 0.f));
        o.z = pack2(fmaxf(acc[4] + bb.x, 0.f), fmaxf(acc[5] + bb.y, 0.f));
        o.w = pack2(fmaxf(acc[6] + bb.z, 0.f), fmaxf(acc[7] + bb.w, 0.f));
        reinterpret_cast<uint4*>(out)[(size_t)n * 32 + q] = o;
    }
}

// ---------------------------------------------------------------------------
// Pool stage 1: partial sums. Grid (G, 8 strides), block 128 (one pair each).
// Writes partial[(g*8+s)*256 + ch] unconditionally (zero when range empty).
// ---------------------------------------------------------------------------
__device__ __forceinline__ int lower_bound_i(const int* a, int n, int val) {
    int lo = 0, hi = n;
    while (lo < hi) {
        int mid = (lo + hi) >> 1;
        if (a[mid] < val) lo = mid + 1; else hi = mid;
    }
    return lo;
}

__global__ __launch_bounds__(128) void k_pool_part(const unsigned* __restrict__ H,
                                                   const int* __restrict__ batch,
                                                   float* __restrict__ partial, int N) {
    const int g = blockIdx.x;
    const int s = blockIdx.y;
    const int p = threadIdx.x;
    const int lo = lower_bound_i(batch, N, g);
    const int hi = lower_bound_i(batch, N, g + 1);
    float sx = 0.f, sy = 0.f;
    for (int n = lo + s; n < hi; n += 8) {
        unsigned u = H[(size_t)n * 128 + p];
        sx += bf16lo(u);
        sy += bf16hi(u);
    }
    float2 v; v.x = sx; v.y = sy;
    reinterpret_cast<float2*>(partial)[(size_t)(g * 8 + s) * 128 + p] = v;
}

// ---------------------------------------------------------------------------
// Classifier (+ pool stage 2): pooled = sum_s partial / cnt; logits; log_softmax.
// ---------------------------------------------------------------------------
__global__ __launch_bounds__(256) void k_cls(const float* __restrict__ partial,
                                             const int* __restrict__ batch,
                                             const float* __restrict__ Wlin,
                                             const float* __restrict__ blin,
                                             float* __restrict__ out, int N) {
    __shared__ float part[NCLS][HIDDEN];
    const int g = blockIdx.x;
    const int t = threadIdx.x;
    const int lo = lower_bound_i(batch, N, g);
    const int hi = lower_bound_i(batch, N, g + 1);
    float p = 0.f;
#pragma unroll
    for (int s = 0; s < 8; ++s) p += partial[(size_t)(g * 8 + s) * HIDDEN + t];
    p /= fmaxf((float)(hi - lo), 1.f);
#pragma unroll
    for (int c = 0; c < NCLS; ++c) part[c][t] = p * Wlin[(size_t)t * NCLS + c];
    __syncthreads();
    for (int off = 128; off >= 1; off >>= 1) {
        if (t < off) {
#pragma unroll
            for (int c = 0; c < NCLS; ++c) part[c][t] += part[c][t + off];
        }
        __syncthreads();
    }
    if (t == 0) {
        float lg[NCLS];
        float m = -INFINITY;
#pragma unroll
        for (int c = 0; c < NCLS; ++c) {
            lg[c] = part[c][0] + blin[c];
            m = fmaxf(m, lg[c]);
        }
        float se = 0.f;
#pragma unroll
        for (int c = 0; c < NCLS; ++c) se += expf(lg[c] - m);
        float lse = m + logf(se);
#pragma unroll
        for (int c = 0; c < NCLS; ++c) out[(size_t)g * NCLS + c] = lg[c] - lse;
    }
}

// ---------------------------------------------------------------------------

extern "C" void kernel_launch(void* const* d_in, const int* in_sizes, int n_in,
                              void* d_out, int out_size, void* d_ws, size_t ws_size,
                              hipStream_t stream) {
    const float* x    = (const float*)d_in[0];
    const float* W1   = (const float*)d_in[1];
    const float* b1   = (const float*)d_in[2];
    const float* W2   = (const float*)d_in[3];
    const float* b2   = (const float*)d_in[4];
    const float* W3   = (const float*)d_in[5];
    const float* b3   = (const float*)d_in[6];
    const float* Wlin = (const float*)d_in[7];
    const float* blin = (const float*)d_in[8];
    const int*   eidx = (const int*)d_in[9];
    const int*   batch= (const int*)d_in[10];
    float* out = (float*)d_out;

    const int N = in_sizes[0] / HIDDEN;      // 10000
    const int E = in_sizes[9] / 2;           // 320000
    const int G = out_size / NCLS;           // 64
    const int Mp = (N + 63) & ~63;           // 10048

    const int* src = eidx;
    const int* dst = eidx + E;

    char* base = (char*)d_ws;
    size_t off = 0;
    auto alloc = [&](size_t bytes) -> void* {
        void* p = base + off;
        off = (off + bytes + 255) & ~(size_t)255;
        return p;
    };
    int*      ecnt     = (int*)     alloc((size_t)N * sizeof(int));
    int*      cursor   = (int*)     alloc((size_t)N * sizeof(int));
    float*    dinv     = (float*)   alloc((size_t)N * sizeof(float));
    int*      rowstart = (int*)     alloc((size_t)(N + 1) * sizeof(int));
    uint2*    csr      = (uint2*)   alloc((size_t)E * sizeof(uint2));
    unsigned* x16      = (unsigned*)alloc((size_t)Mp * 128 * sizeof(unsigned));
    unsigned* hA       = (unsigned*)alloc((size_t)Mp * 128 * sizeof(unsigned));
    unsigned* hB       = (unsigned*)alloc((size_t)Mp * 128 * sizeof(unsigned));
    short8*   Wp1      = (short8*)  alloc((size_t)8192 * sizeof(short8));
    short8*   Wp2      = (short8*)  alloc((size_t)8192 * sizeof(short8));
    short8*   Wp3      = (short8*)  alloc((size_t)8192 * sizeof(short8));
    float*    partial  = (float*)   alloc((size_t)G * 8 * HIDDEN * sizeof(float));
    (void)ws_size;

    const int T = 256;
    // --- graph preprocessing ---
    k_init <<<(N + T - 1) / T, T, 0, stream>>>(ecnt, cursor, N);
    k_count<<<(E + T - 1) / T, T, 0, stream>>>(dst, ecnt, E);
    k_dinv <<<(N + T - 1) / T, T, 0, stream>>>(ecnt, dinv, N);
    k_scan <<<1, 1024, 0, stream>>>(ecnt, rowstart, N, E);
    k_fill <<<(E + T - 1) / T, T, 0, stream>>>(src, dst, dinv, rowstart, cursor, csr, E);
    // --- dtype prep ---
    const int n4 = N * HIDDEN / 4;
    k_cvt  <<<(n4 + T - 1) / T, T, 0, stream>>>(x, x16, n4);
    k_packW<<<8192 / T, T, 0, stream>>>(W1, Wp1);
    k_packW<<<8192 / T, T, 0, stream>>>(W2, Wp2);
    k_packW<<<8192 / T, T, 0, stream>>>(W3, Wp3);

    const dim3 ggrid(Mp / 64, 4);
    // --- layer 1 ---
    k_gemm<<<ggrid, T, 0, stream>>>((const unsigned short*)x16, Wp1, (unsigned short*)hA);
    k_agg <<<N, 64, 0, stream>>>(hA, csr, rowstart, dinv, b1, hB);
    // --- layer 2 ---
    k_gemm<<<ggrid, T, 0, stream>>>((const unsigned short*)hB, Wp2, (unsigned short*)hA);
    k_agg <<<N, 64, 0, stream>>>(hA, csr, rowstart, dinv, b2, hB);
    // --- layer 3 ---
    k_gemm<<<ggrid, T, 0, stream>>>((const unsigned short*)hB, Wp3, (unsigned short*)hA);
    k_agg <<<N, 64, 0, stream>>>(hA, csr, rowstart, dinv, b3, hB);
    // --- pool (2-stage, deterministic) + classifier ---
    k_pool_part<<<dim3(G, 8), 128, 0, stream>>>(hB, batch, partial, N);
    k_cls <<<G, T, 0, stream>>>(partial, batch, Wlin, blin, out, N);
}